// Round 2
// baseline (191.480 us; speedup 1.0000x reference)
//
#include <hip/hip_runtime.h>
#include <hip/hip_cooperative_groups.h>
#include <math.h>

#define KK 32
#define CC 256

namespace cg = cooperative_groups;

// Phase-disjoint LDS overlay (xs/xc/covm/part8/meanv/stdv live outside):
//   phase 1a: rowlds  (W1 2-row staging for A)
//   phase 2 : A_ch    (256-row chunk of A)
//   phase 3 : W2s     (16x512 W2 tile)
//   phase 4 : att     (softmax scratch)
union UPhase {
    float rowlds[2][1056];        //  8,448 B
    float A_ch[256][33];          // 33,792 B
    float W2s[16][512];           // 32,768 B
    float att[KK][KK + 1];        //  4,224 B
};

// One cooperative kernel, 256 blocks (= (b,m)) x 256 threads, 1 block/CU.
// Phase 1: stage x (stays in LDS through phase 4) + A rows; mean; center->xc;
//          cov (BIT-EXACT sequential fma chain); adj -> global + LDS (covm).
// Phase 2: h = gelu(A @ mean)  (mean straight from LDS; h -> global [b][c][m])
// Phase 3: block remap (b,og): e = sigmoid(W2 @ h) -> e_ws [b][m][o]
// Phase 4: masked softmax (mask from LDS adj) + att @ x (xs still in LDS).
__global__ __launch_bounds__(256) void fused_kernel(
    const float* __restrict__ x, const float* __restrict__ W1,
    const float* __restrict__ W2, float* __restrict__ A_ws,
    float* __restrict__ h_ws, float* __restrict__ e_ws,
    float* __restrict__ out, float* __restrict__ adj_out)
{
    __shared__ float xs[KK][260];     // original x: phases 1 & 4 (16B-aligned rows)
    __shared__ float xc[KK][258];     // centered x: phase 1 (8B-aligned rows)
    __shared__ UPhase U;
    __shared__ float covm[KK][KK + 1]; // cov, then adj (survives to phase 4)
    __shared__ float part8[256];
    __shared__ float meanv[KK];
    __shared__ float stdv[KK];

    cg::grid_group grid = cg::this_grid();
    const int t  = threadIdx.x;
    const int bm = blockIdx.x;            // 0..255
    const int b  = bm >> 6, m = bm & 63;

    // ---------------- Phase 1: stats + A ------------------------------------
    {   // stage W1 rows 2bm, 2bm+1 for A (hidden under x staging)
        const float* wr = W1 + (size_t)bm * 2048;
        #pragma unroll
        for (int u = 0; u < 2; ++u) {
            const int e4 = t + u * 256;
            const int q  = e4 >> 8;                  // row 0..1
            const int e  = (e4 & 255) * 4;           // elem 0..1023
            const float4 v = *(const float4*)(wr + q * 1024 + e);
            const int f = (e >> 5) * 33 + (e & 31);  // same transform as mlp1
            U.rowlds[q][f] = v.x; U.rowlds[q][f + 1] = v.y;
            U.rowlds[q][f + 2] = v.z; U.rowlds[q][f + 3] = v.w;
        }
    }
    const float* xp = x + (size_t)bm * (KK * CC);
    #pragma unroll
    for (int s = 0; s < 8; ++s) {
        const int e = s * 1024 + t * 4;
        const float4 v = *(const float4*)(xp + e);
        *(float4*)&xs[e >> 8][e & 255] = v;
    }
    __syncthreads();
    if (t < 64) {   // A rows: bit-identical per-row reduction order to mlp1
        const int k = t & 31, q = t >> 5;
        float rs = 0.f, cs = 0.f;
        #pragma unroll
        for (int j = 0; j < 32; ++j) rs += U.rowlds[q][k * 33 + j];
        #pragma unroll
        for (int i = 0; i < 32; ++i) cs += U.rowlds[q][i * 33 + k];
        A_ws[(size_t)(bm * 2 + q) * 32 + k] =
            0.5f * rs + cs - 0.5f * U.rowlds[q][k * 34];
    }
    {   // row-mean partials (identical tree)
        const int i = t >> 3, part = t & 7;
        float s = 0.f;
        const int c0 = part * 32;
        #pragma unroll
        for (int c = 0; c < 32; ++c) s += xs[i][c0 + c];
        part8[t] = s;
    }
    __syncthreads();
    if (t < KK) {
        float s = 0.f;
        #pragma unroll
        for (int k = 0; k < 8; ++k) s += part8[t * 8 + k];
        meanv[t] = s * (1.0f / CC);
    }
    __syncthreads();
    {   // center into xc (xs preserved for phase 4) — same sub, same bits
        const int r = t >> 3, c0 = (t & 7) * 32;
        const float mv = meanv[r];
        #pragma unroll
        for (int c = 0; c < 32; ++c) xc[r][c0 + c] = xs[r][c0 + c] - mv;
    }
    __syncthreads();
    if (t < 136) {
        int rem = t, r = 0;
        while (rem >= 16 - r) { rem -= 16 - r; ++r; }
        const int ti = r, tj = r + rem;
        const int i0 = 2 * ti, i1 = i0 + 1, j0 = 2 * tj, j1 = j0 + 1;
        float c00 = 0.f, c01 = 0.f, c10 = 0.f, c11 = 0.f;
        #pragma unroll 4
        for (int c = 0; c < CC; c += 2) {
            const float2 a0 = *(const float2*)&xc[i0][c];
            const float2 a1 = *(const float2*)&xc[i1][c];
            const float2 b0 = *(const float2*)&xc[j0][c];
            const float2 b1 = *(const float2*)&xc[j1][c];
            // sequential fma chain per accumulator — bit-exact
            c00 += a0.x * b0.x; c00 += a0.y * b0.y;
            c01 += a0.x * b1.x; c01 += a0.y * b1.y;
            c10 += a1.x * b0.x; c10 += a1.y * b0.y;
            c11 += a1.x * b1.x; c11 += a1.y * b1.y;
        }
        c00 *= (1.0f / (CC - 1)); c01 *= (1.0f / (CC - 1));
        c10 *= (1.0f / (CC - 1)); c11 *= (1.0f / (CC - 1));
        covm[i0][j0] = c00; covm[i0][j1] = c01;
        covm[i1][j0] = c10; covm[i1][j1] = c11;
        covm[j0][i0] = c00; covm[j1][i0] = c01;
        covm[j0][i1] = c10; covm[j1][i1] = c11;
    }
    __syncthreads();
    if (t < KK) stdv[t] = sqrtf(covm[t][t]);
    __syncthreads();
    #pragma unroll
    for (int k = 0; k < 4; ++k) {
        const int pair = t + k * 256;
        const int i = pair >> 5, j = pair & 31;
        const float av = covm[i][j] / (stdv[i] * stdv[j]);
        adj_out[(size_t)bm * 1024 + pair] = av;
        covm[i][j] = av;                  // keep adj in LDS for phase-4 mask
    }
    grid.sync();   // ① A_ws complete

    // ---------------- Phase 2: h = gelu(A @ mean) ---------------------------
    for (int ch = 0; ch < 2; ++ch) {
        if (ch) __syncthreads();          // protect A_ch reuse
        const float* ap = A_ws + (size_t)ch * 8192;
        #pragma unroll
        for (int u = 0; u < 8; ++u) {     // stage 256 rows of A, coalesced
            const int e4 = t + u * 256;
            const float4 v = *(const float4*)(ap + e4 * 4);
            const int ol = e4 >> 3, k0 = (e4 & 7) * 4;
            U.A_ch[ol][k0]     = v.x; U.A_ch[ol][k0 + 1] = v.y;
            U.A_ch[ol][k0 + 2] = v.z; U.A_ch[ol][k0 + 3] = v.w;
        }
        __syncthreads();
        float s = 0.f;
        #pragma unroll
        for (int k = 0; k < 32; ++k) s += U.A_ch[t][k] * meanv[k];  // k-ascending
        const float g = 0.5f * s * (1.0f + erff(s * 0.70710678118654752f));
        h_ws[(size_t)(b * 512 + ch * 256 + t) * 64 + m] = g;        // [b][c][m]
    }
    grid.sync();   // ② h_ws complete

    // ---------------- Phase 3: e = sigmoid(W2 @ h), block remap (b,og) ------
    {
        const int b3 = bm >> 6;
        const int ob = (bm & 63) * 16;
        const int m3 = t & 63, ow = t >> 6, ol = ow * 4;
        const float* src = W2 + (size_t)ob * 512;
        #pragma unroll
        for (int u = 0; u < 8; ++u) {
            const int e4 = t + u * 256;
            const float4 v = *(const float4*)(src + e4 * 4);
            *(float4*)&U.W2s[e4 >> 7][(e4 & 127) * 4] = v;
        }
        __syncthreads();
        const float* hb = h_ws + (size_t)b3 * 512 * 64 + m3;
        float acc[4] = {0.f, 0.f, 0.f, 0.f};
        #pragma unroll 4
        for (int c = 0; c < 512; c += 4) {
            const float hv0 = hb[(size_t)(c + 0) * 64];
            const float hv1 = hb[(size_t)(c + 1) * 64];
            const float hv2 = hb[(size_t)(c + 2) * 64];
            const float hv3 = hb[(size_t)(c + 3) * 64];
            #pragma unroll
            for (int q = 0; q < 4; ++q) {
                const float4 w = *(const float4*)&U.W2s[ol + q][c];  // broadcast
                acc[q] += w.x * hv0;
                acc[q] += w.y * hv1;
                acc[q] += w.z * hv2;
                acc[q] += w.w * hv3;
            }
        }
        float4 sv;
        sv.x = 1.0f / (1.0f + expf(-acc[0]));
        sv.y = 1.0f / (1.0f + expf(-acc[1]));
        sv.z = 1.0f / (1.0f + expf(-acc[2]));
        sv.w = 1.0f / (1.0f + expf(-acc[3]));
        *(float4*)&e_ws[(size_t)(b3 * 64 + m3) * 1024 + ob + ol] = sv;
    }
    grid.sync();   // ③ e_ws complete

    // ---------------- Phase 4: masked softmax + att @ x ---------------------
    {
        const int p0 = 4 * t;
        const float4 ev4 = *(const float4*)&e_ws[(size_t)(b * 64 + m) * 1024 + p0];
        const int i = p0 >> 5, j0 = p0 & 31;
        U.att[i][j0]     = (covm[i][j0]     > 0.f) ? ev4.x : -INFINITY;
        U.att[i][j0 + 1] = (covm[i][j0 + 1] > 0.f) ? ev4.y : -INFINITY;
        U.att[i][j0 + 2] = (covm[i][j0 + 2] > 0.f) ? ev4.z : -INFINITY;
        U.att[i][j0 + 3] = (covm[i][j0 + 3] > 0.f) ? ev4.w : -INFINITY;
    }
    __syncthreads();
    if (t < KK) {
        float mx = -INFINITY;
        #pragma unroll
        for (int j = 0; j < KK; ++j) mx = fmaxf(mx, U.att[t][j]);
        float s = 0.f;
        #pragma unroll
        for (int j = 0; j < KK; ++j) {
            const float v = expf(U.att[t][j] - mx);
            U.att[t][j] = v;
            s += v;
        }
        const float inv = 1.0f / s;
        #pragma unroll
        for (int j = 0; j < KK; ++j) U.att[t][j] *= inv;
    }
    __syncthreads();
    {
        const int c8 = t & 31, iq = t >> 5;
        const int i0 = iq * 4;
        const int cA = 4 * c8, cB = 128 + 4 * c8;
        float4 accA[4], accB[4];
        #pragma unroll
        for (int r = 0; r < 4; ++r) {
            accA[r] = make_float4(0.f, 0.f, 0.f, 0.f);
            accB[r] = make_float4(0.f, 0.f, 0.f, 0.f);
        }
        #pragma unroll 2
        for (int j = 0; j < KK; ++j) {
            const float4 xa = *(const float4*)&xs[j][cA];
            const float4 xb = *(const float4*)&xs[j][cB];
            #pragma unroll
            for (int r = 0; r < 4; ++r) {
                const float av = U.att[i0 + r][j];
                accA[r].x += av * xa.x; accA[r].y += av * xa.y;
                accA[r].z += av * xa.z; accA[r].w += av * xa.w;
                accB[r].x += av * xb.x; accB[r].y += av * xb.y;
                accB[r].z += av * xb.z; accB[r].w += av * xb.w;
            }
        }
        float* op = out + (size_t)bm * (KK * CC);
        #pragma unroll
        for (int r = 0; r < 4; ++r) {
            *(float4*)(op + (size_t)(i0 + r) * CC + cA) = accA[r];
            *(float4*)(op + (size_t)(i0 + r) * CC + cB) = accB[r];
        }
    }
}

extern "C" void kernel_launch(void* const* d_in, const int* in_sizes, int n_in,
                              void* d_out, int out_size, void* d_ws, size_t ws_size,
                              hipStream_t stream) {
    const float* x  = (const float*)d_in[0];   // (4,64,32,256)
    const float* W1 = (const float*)d_in[1];   // (512,1024)
    const float* W2 = (const float*)d_in[2];   // (1024,512)
    float* out     = (float*)d_out;                       // 2,097,152 floats
    float* adj_out = out + (size_t)4 * 64 * 32 * 256;     // +262,144 floats

    float* A_ws = (float*)d_ws;                       // 512*32   =  16,384
    float* h_ws = A_ws + 16384;                       // 4*512*64 = 131,072
    float* e_ws = h_ws + 131072;                      // 4*64*1024= 262,144

    void* args[] = { (void*)&x, (void*)&W1, (void*)&W2, (void*)&A_ws,
                     (void*)&h_ws, (void*)&e_ws, (void*)&out, (void*)&adj_out };
    hipLaunchCooperativeKernel((void*)fused_kernel, dim3(256), dim3(256),
                               args, 0, stream);
}

// Round 3
// 115.740 us; speedup vs baseline: 1.6544x; 1.6544x over previous
//
#include <hip/hip_runtime.h>
#include <math.h>

#define KK 32
#define CC 256

// ---------------------------------------------------------------------------
// Kernel 1: per-(b,m) stats, 256 blocks x 256 threads (1 per CU, no tail).
// NEW vs R0: each block ALSO computes 2 rows of A from W1 (rows 2bm, 2bm+1),
// staged concurrently with x and reduced while other threads do mean partials
// — hidden under existing latency (pattern verified bit-exact in R2 coop).
// All stats arithmetic is byte-identical to R0 (cov chain is knife-edge).
// ---------------------------------------------------------------------------
__global__ __launch_bounds__(256) void prep_kernel(
    const float* __restrict__ x, const float* __restrict__ W1,
    float* __restrict__ mean_ws, float* __restrict__ A_ws,
    float* __restrict__ adj_out)
{
    __shared__ float xs[KK][258];
    __shared__ float rowlds[2][1056];
    __shared__ float part8[256];
    __shared__ float meanv[KK];
    __shared__ float covm[KK][KK + 1];
    __shared__ float stdv[KK];

    const int t  = threadIdx.x;
    const int bm = blockIdx.x;            // 0..255
    const int b  = bm >> 6, m = bm & 63;
    const float* xp = x + (size_t)bm * (KK * CC);

    {   // stage W1 rows 2bm, 2bm+1 (for A) — same transform as verified R2
        const float* wr = W1 + (size_t)bm * 2048;
        #pragma unroll
        for (int u = 0; u < 2; ++u) {
            const int e4 = t + u * 256;
            const int q  = e4 >> 8;                  // row 0..1
            const int e  = (e4 & 255) * 4;           // elem 0..1023
            const float4 v = *(const float4*)(wr + q * 1024 + e);
            const int f = (e >> 5) * 33 + (e & 31);
            rowlds[q][f] = v.x; rowlds[q][f + 1] = v.y;
            rowlds[q][f + 2] = v.z; rowlds[q][f + 3] = v.w;
        }
    }
    #pragma unroll
    for (int s = 0; s < 8; ++s) {
        const int e = s * 1024 + t * 4;
        const float4 v = *(const float4*)(xp + e);
        const int i = e >> 8, col = e & 255;
        xs[i][col] = v.x; xs[i][col + 1] = v.y;
        xs[i][col + 2] = v.z; xs[i][col + 3] = v.w;
    }
    __syncthreads();
    if (t < 64) {   // A rows: bit-identical reduction order (verified R2)
        const int k = t & 31, q = t >> 5;
        float rs = 0.f, cs = 0.f;
        #pragma unroll
        for (int j = 0; j < 32; ++j) rs += rowlds[q][k * 33 + j];
        #pragma unroll
        for (int i = 0; i < 32; ++i) cs += rowlds[q][i * 33 + k];
        A_ws[(size_t)(bm * 2 + q) * 32 + k] =
            0.5f * rs + cs - 0.5f * rowlds[q][k * 34];
    }
    {   // row-mean partials (identical tree to R0)
        const int i = t >> 3, part = t & 7;
        float s = 0.f;
        const int c0 = part * 32;
        #pragma unroll
        for (int c = 0; c < 32; ++c) s += xs[i][c0 + c];
        part8[t] = s;
    }
    __syncthreads();
    if (t < KK) {
        float s = 0.f;
        #pragma unroll
        for (int k = 0; k < 8; ++k) s += part8[t * 8 + k];
        meanv[t] = s * (1.0f / CC);
        mean_ws[(size_t)(b * 32 + t) * 64 + m] = meanv[t];
    }
    __syncthreads();
    {
        const int r = t >> 3, c0 = (t & 7) * 32;
        const float mv = meanv[r];
        #pragma unroll
        for (int c = 0; c < 32; ++c) xs[r][c0 + c] -= mv;
    }
    __syncthreads();
    if (t < 136) {
        int rem = t, r = 0;
        while (rem >= 16 - r) { rem -= 16 - r; ++r; }
        const int ti = r, tj = r + rem;
        const int i0 = 2 * ti, i1 = i0 + 1, j0 = 2 * tj, j1 = j0 + 1;
        float c00 = 0.f, c01 = 0.f, c10 = 0.f, c11 = 0.f;
        #pragma unroll 4
        for (int c = 0; c < CC; c += 2) {
            const float2 a0 = *(const float2*)&xs[i0][c];
            const float2 a1 = *(const float2*)&xs[i1][c];
            const float2 b0 = *(const float2*)&xs[j0][c];
            const float2 b1 = *(const float2*)&xs[j1][c];
            // sequential fma chain per accumulator — bit-exact
            c00 += a0.x * b0.x; c00 += a0.y * b0.y;
            c01 += a0.x * b1.x; c01 += a0.y * b1.y;
            c10 += a1.x * b0.x; c10 += a1.y * b0.y;
            c11 += a1.x * b1.x; c11 += a1.y * b1.y;
        }
        c00 *= (1.0f / (CC - 1)); c01 *= (1.0f / (CC - 1));
        c10 *= (1.0f / (CC - 1)); c11 *= (1.0f / (CC - 1));
        covm[i0][j0] = c00; covm[i0][j1] = c01;
        covm[i1][j0] = c10; covm[i1][j1] = c11;
        covm[j0][i0] = c00; covm[j1][i0] = c01;
        covm[j0][i1] = c10; covm[j1][i1] = c11;
    }
    __syncthreads();
    if (t < KK) stdv[t] = sqrtf(covm[t][t]);
    __syncthreads();
    #pragma unroll
    for (int k = 0; k < 4; ++k) {
        const int pair = t + k * 256;
        const int i = pair >> 5, j = pair & 31;
        adj_out[(size_t)bm * 1024 + pair] = covm[i][j] / (stdv[i] * stdv[j]);
    }
}

// ---------------------------------------------------------------------------
// Kernel 2 (tiny): h = gelu(A @ mean) per (b,m). 256 blocks x 256 threads,
// thread t computes o = 2t, 2t+1. Chain k-ascending — bit-exact (R1-verified).
// h layout [b][m][c] -> float4 loads in the e-kernel.
// ---------------------------------------------------------------------------
__global__ __launch_bounds__(256) void h_kernel(
    const float* __restrict__ A_ws, const float* __restrict__ mean_ws,
    float* __restrict__ h_ws)
{
    __shared__ float meanv[KK];
    const int t  = threadIdx.x;
    const int bm = blockIdx.x;
    const int b  = bm >> 6, m = bm & 63;
    if (t < KK) meanv[t] = mean_ws[(size_t)(b * 32 + t) * 64 + m];
    __syncthreads();

    const int o0 = t * 2;
    const float* a0 = A_ws + (size_t)o0 * 32;
    const float* a1 = a0 + 32;
    float r0[32], r1[32];
    #pragma unroll
    for (int u = 0; u < 8; ++u) {
        *(float4*)&r0[u * 4] = *(const float4*)(a0 + u * 4);
        *(float4*)&r1[u * 4] = *(const float4*)(a1 + u * 4);
    }
    float s0 = 0.f, s1 = 0.f;
    #pragma unroll
    for (int k = 0; k < 32; ++k) {
        s0 += r0[k] * meanv[k];    // k-ascending, bit-exact
        s1 += r1[k] * meanv[k];
    }
    const float g0 = 0.5f * s0 * (1.0f + erff(s0 * 0.70710678118654752f));
    const float g1 = 0.5f * s1 * (1.0f + erff(s1 * 0.70710678118654752f));
    float2 st; st.x = g0; st.y = g1;
    *(float2*)&h_ws[(size_t)(b * 64 + m) * 512 + o0] = st;
}

// ---------------------------------------------------------------------------
// Kernel 3: e = sigmoid(W2 @ h). NEW: 8 outputs/block -> grid (128,4) = 512
// blocks = 2 blocks/CU (wave-level latency overlap; W2s tile 16 KB). Block =
// 64 m x 4 waves, each wave owns 2 o's. Per-(o,m) accumulation chain is the
// identical c-ascending x,y,z,w fmac sequence (bit-exact). h loads: per-thread
// float4 from [b][m][c] (R1-verified). e_ws layout [b][m][o].
// ---------------------------------------------------------------------------
__global__ __launch_bounds__(256) void e_kernel(
    const float* __restrict__ W2, const float* __restrict__ h_ws,
    float* __restrict__ e_ws)
{
    __shared__ float W2s[8][512];      // 16 KB
    const int m  = threadIdx.x;        // 0..63
    const int ow = threadIdx.y;        // 0..3
    const int b  = blockIdx.y;
    const int ob = blockIdx.x * 8;

    {
        const int t = ow * 64 + m;
        const float* src = W2 + (size_t)ob * 512;
        #pragma unroll
        for (int u = 0; u < 4; ++u) {
            const int e4 = t + u * 256;            // 1024 float4 total
            const float4 v = *(const float4*)(src + e4 * 4);
            *(float4*)&W2s[e4 >> 7][(e4 & 127) * 4] = v;
        }
    }
    __syncthreads();

    const float* hb = h_ws + (size_t)(b * 64 + m) * 512;
    float acc[2] = {0.f, 0.f};
    const int ol = ow * 2;

    #pragma unroll 4
    for (int c = 0; c < 512; c += 4) {
        const float4 hv = *(const float4*)(hb + c);
        #pragma unroll
        for (int q = 0; q < 2; ++q) {
            const float4 w = *(const float4*)&W2s[ol + q][c];  // broadcast
            acc[q] += w.x * hv.x;
            acc[q] += w.y * hv.y;
            acc[q] += w.z * hv.z;
            acc[q] += w.w * hv.w;
        }
    }
    float2 sv;
    sv.x = 1.0f / (1.0f + expf(-acc[0]));
    sv.y = 1.0f / (1.0f + expf(-acc[1]));
    *(float2*)&e_ws[(size_t)(b * 64 + m) * 1024 + ob + ol] = sv;
}

// ---------------------------------------------------------------------------
// Kernel 4: masked softmax (mask adj>0) + att @ x. 256 blocks (b,m).
// Byte-identical arithmetic to R0 (which measured 100.1).
// ---------------------------------------------------------------------------
__global__ __launch_bounds__(256) void softmax_out_kernel(
    const float* __restrict__ x, const float* __restrict__ e_ws,
    const float* __restrict__ adj, float* __restrict__ out)
{
    __shared__ float xs[KK][260];
    __shared__ float att[KK][KK + 1];
    const int bm = blockIdx.x;
    const int b  = bm >> 6, m = bm & 63;
    const int t  = threadIdx.x;
    const float* xp = x + (size_t)bm * (KK * CC);

    #pragma unroll
    for (int s = 0; s < 8; ++s) {
        const int e = s * 1024 + t * 4;
        const float4 v = *(const float4*)(xp + e);
        *(float4*)&xs[e >> 8][e & 255] = v;
    }
    {
        const int p0 = 4 * t;
        const float4 ev4 = *(const float4*)&e_ws[(size_t)(b * 64 + m) * 1024 + p0];
        const float4 aj4 = *(const float4*)&adj[(size_t)bm * 1024 + p0];
        const int i = p0 >> 5, j0 = p0 & 31;
        att[i][j0]     = (aj4.x > 0.f) ? ev4.x : -INFINITY;
        att[i][j0 + 1] = (aj4.y > 0.f) ? ev4.y : -INFINITY;
        att[i][j0 + 2] = (aj4.z > 0.f) ? ev4.z : -INFINITY;
        att[i][j0 + 3] = (aj4.w > 0.f) ? ev4.w : -INFINITY;
    }
    __syncthreads();
    if (t < KK) {
        float mx = -INFINITY;
        #pragma unroll
        for (int j = 0; j < KK; ++j) mx = fmaxf(mx, att[t][j]);
        float s = 0.f;
        #pragma unroll
        for (int j = 0; j < KK; ++j) {
            const float v = expf(att[t][j] - mx);
            att[t][j] = v;
            s += v;
        }
        const float inv = 1.0f / s;
        #pragma unroll
        for (int j = 0; j < KK; ++j) att[t][j] *= inv;
    }
    __syncthreads();

    const int c8 = t & 31, iq = t >> 5;
    const int i0 = iq * 4;
    const int cA = 4 * c8, cB = 128 + 4 * c8;
    float4 accA[4], accB[4];
    #pragma unroll
    for (int r = 0; r < 4; ++r) {
        accA[r] = make_float4(0.f, 0.f, 0.f, 0.f);
        accB[r] = make_float4(0.f, 0.f, 0.f, 0.f);
    }
    #pragma unroll 2
    for (int j = 0; j < KK; ++j) {
        const float4 xa = *(const float4*)&xs[j][cA];
        const float4 xb = *(const float4*)&xs[j][cB];
        #pragma unroll
        for (int r = 0; r < 4; ++r) {
            const float av = att[i0 + r][j];
            accA[r].x += av * xa.x; accA[r].y += av * xa.y;
            accA[r].z += av * xa.z; accA[r].w += av * xa.w;
            accB[r].x += av * xb.x; accB[r].y += av * xb.y;
            accB[r].z += av * xb.z; accB[r].w += av * xb.w;
        }
    }
    float* op = out + (size_t)bm * (KK * CC);
    #pragma unroll
    for (int r = 0; r < 4; ++r) {
        *(float4*)(op + (size_t)(i0 + r) * CC + cA) = accA[r];
        *(float4*)(op + (size_t)(i0 + r) * CC + cB) = accB[r];
    }
}

extern "C" void kernel_launch(void* const* d_in, const int* in_sizes, int n_in,
                              void* d_out, int out_size, void* d_ws, size_t ws_size,
                              hipStream_t stream) {
    const float* x  = (const float*)d_in[0];   // (4,64,32,256)
    const float* W1 = (const float*)d_in[1];   // (512,1024)
    const float* W2 = (const float*)d_in[2];   // (1024,512)
    float* out     = (float*)d_out;                       // 2,097,152 floats
    float* adj_out = out + (size_t)4 * 64 * 32 * 256;     // +262,144 floats

    float* mean_ws = (float*)d_ws;                    // 4*32*64   =   8,192
    float* A_ws    = mean_ws + 8192;                  // 512*32    =  16,384
    float* h_ws    = A_ws + 16384;                    // 4*64*512  = 131,072
    float* e_ws    = h_ws + 131072;                   // 4*64*1024 = 262,144

    prep_kernel<<<256, 256, 0, stream>>>(x, W1, mean_ws, A_ws, adj_out);
    h_kernel<<<256, 256, 0, stream>>>(A_ws, mean_ws, h_ws);
    e_kernel<<<dim3(128, 4), dim3(64, 4), 0, stream>>>(W2, h_ws, e_ws);
    softmax_out_kernel<<<256, 256, 0, stream>>>(x, e_ws, adj_out, out);
}

// Round 4
// 107.575 us; speedup vs baseline: 1.7800x; 1.0759x over previous
//
#include <hip/hip_runtime.h>
#include <math.h>

#define KK 32
#define CC 256

// ---------------------------------------------------------------------------
// Kernel 1: per-(b,m) stats, 256 blocks x 256 threads. Each block ALSO
// computes 2 rows of A from W1 (rows 2bm,2bm+1) — staged under x staging,
// verified bit-exact in R2/R3. All stats arithmetic byte-identical to R0
// (cov chain is knife-edge for the adj>0 mask).
// ---------------------------------------------------------------------------
__global__ __launch_bounds__(256) void prep_kernel(
    const float* __restrict__ x, const float* __restrict__ W1,
    float* __restrict__ mean_ws, float* __restrict__ A_ws,
    float* __restrict__ adj_out)
{
    __shared__ float xs[KK][258];
    __shared__ float rowlds[2][1056];
    __shared__ float part8[256];
    __shared__ float meanv[KK];
    __shared__ float covm[KK][KK + 1];
    __shared__ float stdv[KK];

    const int t  = threadIdx.x;
    const int bm = blockIdx.x;            // 0..255
    const int b  = bm >> 6, m = bm & 63;
    const float* xp = x + (size_t)bm * (KK * CC);

    {   // stage W1 rows 2bm, 2bm+1 (for A)
        const float* wr = W1 + (size_t)bm * 2048;
        #pragma unroll
        for (int u = 0; u < 2; ++u) {
            const int e4 = t + u * 256;
            const int q  = e4 >> 8;
            const int e  = (e4 & 255) * 4;
            const float4 v = *(const float4*)(wr + q * 1024 + e);
            const int f = (e >> 5) * 33 + (e & 31);
            rowlds[q][f] = v.x; rowlds[q][f + 1] = v.y;
            rowlds[q][f + 2] = v.z; rowlds[q][f + 3] = v.w;
        }
    }
    #pragma unroll
    for (int s = 0; s < 8; ++s) {
        const int e = s * 1024 + t * 4;
        const float4 v = *(const float4*)(xp + e);
        const int i = e >> 8, col = e & 255;
        xs[i][col] = v.x; xs[i][col + 1] = v.y;
        xs[i][col + 2] = v.z; xs[i][col + 3] = v.w;
    }
    __syncthreads();
    if (t < 64) {   // A rows: bit-identical reduction order (verified R2/R3)
        const int k = t & 31, q = t >> 5;
        float rs = 0.f, cs = 0.f;
        #pragma unroll
        for (int j = 0; j < 32; ++j) rs += rowlds[q][k * 33 + j];
        #pragma unroll
        for (int i = 0; i < 32; ++i) cs += rowlds[q][i * 33 + k];
        A_ws[(size_t)(bm * 2 + q) * 32 + k] =
            0.5f * rs + cs - 0.5f * rowlds[q][k * 34];
    }
    {   // row-mean partials (identical tree to R0)
        const int i = t >> 3, part = t & 7;
        float s = 0.f;
        const int c0 = part * 32;
        #pragma unroll
        for (int c = 0; c < 32; ++c) s += xs[i][c0 + c];
        part8[t] = s;
    }
    __syncthreads();
    if (t < KK) {
        float s = 0.f;
        #pragma unroll
        for (int k = 0; k < 8; ++k) s += part8[t * 8 + k];
        meanv[t] = s * (1.0f / CC);
        mean_ws[(size_t)(b * 32 + t) * 64 + m] = meanv[t];
    }
    __syncthreads();
    {
        const int r = t >> 3, c0 = (t & 7) * 32;
        const float mv = meanv[r];
        #pragma unroll
        for (int c = 0; c < 32; ++c) xs[r][c0 + c] -= mv;
    }
    __syncthreads();
    if (t < 136) {
        int rem = t, r = 0;
        while (rem >= 16 - r) { rem -= 16 - r; ++r; }
        const int ti = r, tj = r + rem;
        const int i0 = 2 * ti, i1 = i0 + 1, j0 = 2 * tj, j1 = j0 + 1;
        float c00 = 0.f, c01 = 0.f, c10 = 0.f, c11 = 0.f;
        #pragma unroll 4
        for (int c = 0; c < CC; c += 2) {
            const float2 a0 = *(const float2*)&xs[i0][c];
            const float2 a1 = *(const float2*)&xs[i1][c];
            const float2 b0 = *(const float2*)&xs[j0][c];
            const float2 b1 = *(const float2*)&xs[j1][c];
            // sequential fma chain per accumulator — bit-exact
            c00 += a0.x * b0.x; c00 += a0.y * b0.y;
            c01 += a0.x * b1.x; c01 += a0.y * b1.y;
            c10 += a1.x * b0.x; c10 += a1.y * b0.y;
            c11 += a1.x * b1.x; c11 += a1.y * b1.y;
        }
        c00 *= (1.0f / (CC - 1)); c01 *= (1.0f / (CC - 1));
        c10 *= (1.0f / (CC - 1)); c11 *= (1.0f / (CC - 1));
        covm[i0][j0] = c00; covm[i0][j1] = c01;
        covm[i1][j0] = c10; covm[i1][j1] = c11;
        covm[j0][i0] = c00; covm[j1][i0] = c01;
        covm[j0][i1] = c10; covm[j1][i1] = c11;
    }
    __syncthreads();
    if (t < KK) stdv[t] = sqrtf(covm[t][t]);
    __syncthreads();
    #pragma unroll
    for (int k = 0; k < 4; ++k) {
        const int pair = t + k * 256;
        const int i = pair >> 5, j = pair & 31;
        adj_out[(size_t)bm * 1024 + pair] = covm[i][j] / (stdv[i] * stdv[j]);
    }
}

// ---------------------------------------------------------------------------
// Kernel 2 (tiny): h = gelu(A @ mean), 256 blocks. Thread t -> o = 2t,2t+1.
// Chain k-ascending — bit-exact (verified R1/R3). h layout [b][m][c].
// ---------------------------------------------------------------------------
__global__ __launch_bounds__(256) void h_kernel(
    const float* __restrict__ A_ws, const float* __restrict__ mean_ws,
    float* __restrict__ h_ws)
{
    __shared__ float meanv[KK];
    const int t  = threadIdx.x;
    const int bm = blockIdx.x;
    const int b  = bm >> 6, m = bm & 63;
    if (t < KK) meanv[t] = mean_ws[(size_t)(b * 32 + t) * 64 + m];
    __syncthreads();

    const int o0 = t * 2;
    const float* a0 = A_ws + (size_t)o0 * 32;
    const float* a1 = a0 + 32;
    float r0[32], r1[32];
    #pragma unroll
    for (int u = 0; u < 8; ++u) {
        *(float4*)&r0[u * 4] = *(const float4*)(a0 + u * 4);
        *(float4*)&r1[u * 4] = *(const float4*)(a1 + u * 4);
    }
    float s0 = 0.f, s1 = 0.f;
    #pragma unroll
    for (int k = 0; k < 32; ++k) {
        s0 += r0[k] * meanv[k];    // k-ascending, bit-exact
        s1 += r1[k] * meanv[k];
    }
    const float g0 = 0.5f * s0 * (1.0f + erff(s0 * 0.70710678118654752f));
    const float g1 = 0.5f * s1 * (1.0f + erff(s1 * 0.70710678118654752f));
    float2 st; st.x = g0; st.y = g1;
    *(float2*)&h_ws[(size_t)(b * 64 + m) * 512 + o0] = st;
}

// ---------------------------------------------------------------------------
// Kernel 3: e = sigmoid(W2 @ h). R1-verified version verbatim: grid (64,4),
// 16 o/block, W2s 32 KB, per-thread float4 h loads from [b][m][c]. Acc chain
// c-ascending x,y,z,w — bit-exact. e_ws layout [b][m][o].
// ---------------------------------------------------------------------------
__global__ __launch_bounds__(256) void e_kernel(
    const float* __restrict__ W2, const float* __restrict__ h_ws,
    float* __restrict__ e_ws)
{
    __shared__ float W2s[16][512];     // 32 KB
    const int m  = threadIdx.x;        // 0..63
    const int ow = threadIdx.y;        // 0..3
    const int b  = blockIdx.y;
    const int ob = blockIdx.x * 16;

    {
        const int t = ow * 64 + m;
        const float* src = W2 + (size_t)ob * 512;
        #pragma unroll
        for (int u = 0; u < 8; ++u) {
            const int e4 = t + u * 256;
            const float4 v = *(const float4*)(src + e4 * 4);
            *(float4*)&W2s[e4 >> 7][(e4 & 127) * 4] = v;
        }
    }
    __syncthreads();

    const float* hb = h_ws + (size_t)(b * 64 + m) * 512;
    float acc[4] = {0.f, 0.f, 0.f, 0.f};
    const int ol = ow * 4;

    #pragma unroll 4
    for (int c = 0; c < 512; c += 4) {
        const float4 hv = *(const float4*)(hb + c);
        #pragma unroll
        for (int q = 0; q < 4; ++q) {
            const float4 w = *(const float4*)&W2s[ol + q][c];  // broadcast
            acc[q] += w.x * hv.x;
            acc[q] += w.y * hv.y;
            acc[q] += w.z * hv.z;
            acc[q] += w.w * hv.w;
        }
    }
    float4 sv;
    sv.x = 1.0f / (1.0f + expf(-acc[0]));
    sv.y = 1.0f / (1.0f + expf(-acc[1]));
    sv.z = 1.0f / (1.0f + expf(-acc[2]));
    sv.w = 1.0f / (1.0f + expf(-acc[3]));
    *(float4*)&e_ws[(size_t)(b * 64 + m) * 1024 + ob + ol] = sv;
}

// ---------------------------------------------------------------------------
// Kernel 4: masked softmax + att @ x. NEW: 512 blocks = (bm, column-half).
// Each half-block duplicates the (cheap) mask+softmax — identical
// instruction sequence -> identical att bits — and handles 128 of the 256
// x-columns in the PV product. Half 0's acc chain == R0's accA, half 1's ==
// R0's accB (bit-exact). 2 blocks/CU -> wave-level latency overlap; x
// staging per block halves.
// ---------------------------------------------------------------------------
__global__ __launch_bounds__(256) void softmax_out_kernel(
    const float* __restrict__ x, const float* __restrict__ e_ws,
    const float* __restrict__ adj, float* __restrict__ out)
{
    __shared__ float xs[KK][132];
    __shared__ float att[KK][KK + 1];
    const int bid = blockIdx.x;
    const int bm  = bid >> 1;          // 0..255
    const int ph  = bid & 1;           // column half
    const int b   = bm >> 6, m = bm & 63;
    const int t   = threadIdx.x;
    const int base = ph * 128;
    const float* xp = x + (size_t)bm * (KK * CC) + base;

    #pragma unroll
    for (int s = 0; s < 4; ++s) {      // stage 32 rows x 128 cols
        const int e4  = t + s * 256;   // float4 index
        const int row = e4 >> 5;
        const int col = (e4 & 31) * 4;
        const float4 v = *(const float4*)(xp + (size_t)row * CC + col);
        *(float4*)&xs[row][col] = v;
    }
    {
        const int p0 = 4 * t;
        const float4 ev4 = *(const float4*)&e_ws[(size_t)(b * 64 + m) * 1024 + p0];
        const float4 aj4 = *(const float4*)&adj[(size_t)bm * 1024 + p0];
        const int i = p0 >> 5, j0 = p0 & 31;
        att[i][j0]     = (aj4.x > 0.f) ? ev4.x : -INFINITY;
        att[i][j0 + 1] = (aj4.y > 0.f) ? ev4.y : -INFINITY;
        att[i][j0 + 2] = (aj4.z > 0.f) ? ev4.z : -INFINITY;
        att[i][j0 + 3] = (aj4.w > 0.f) ? ev4.w : -INFINITY;
    }
    __syncthreads();
    if (t < KK) {   // identical serial softmax in both halves -> same bits
        float mx = -INFINITY;
        #pragma unroll
        for (int j = 0; j < KK; ++j) mx = fmaxf(mx, att[t][j]);
        float s = 0.f;
        #pragma unroll
        for (int j = 0; j < KK; ++j) {
            const float v = expf(att[t][j] - mx);
            att[t][j] = v;
            s += v;
        }
        const float inv = 1.0f / s;
        #pragma unroll
        for (int j = 0; j < KK; ++j) att[t][j] *= inv;
    }
    __syncthreads();

    const int c8 = t & 31, iq = t >> 5;
    const int i0 = iq * 4;
    const int cA = 4 * c8;             // local column (0..124)
    float4 accA[4];
    #pragma unroll
    for (int r = 0; r < 4; ++r) accA[r] = make_float4(0.f, 0.f, 0.f, 0.f);
    #pragma unroll 2
    for (int j = 0; j < KK; ++j) {
        const float4 xa = *(const float4*)&xs[j][cA];
        #pragma unroll
        for (int r = 0; r < 4; ++r) {
            const float av = att[i0 + r][j];
            accA[r].x += av * xa.x; accA[r].y += av * xa.y;
            accA[r].z += av * xa.z; accA[r].w += av * xa.w;
        }
    }
    float* op = out + (size_t)bm * (KK * CC) + base;
    #pragma unroll
    for (int r = 0; r < 4; ++r)
        *(float4*)(op + (size_t)(i0 + r) * CC + cA) = accA[r];
}

extern "C" void kernel_launch(void* const* d_in, const int* in_sizes, int n_in,
                              void* d_out, int out_size, void* d_ws, size_t ws_size,
                              hipStream_t stream) {
    const float* x  = (const float*)d_in[0];   // (4,64,32,256)
    const float* W1 = (const float*)d_in[1];   // (512,1024)
    const float* W2 = (const float*)d_in[2];   // (1024,512)
    float* out     = (float*)d_out;                       // 2,097,152 floats
    float* adj_out = out + (size_t)4 * 64 * 32 * 256;     // +262,144 floats

    float* mean_ws = (float*)d_ws;                    // 4*32*64   =   8,192
    float* A_ws    = mean_ws + 8192;                  // 512*32    =  16,384
    float* h_ws    = A_ws + 16384;                    // 4*64*512  = 131,072
    float* e_ws    = h_ws + 131072;                   // 4*64*1024 = 262,144

    prep_kernel<<<256, 256, 0, stream>>>(x, W1, mean_ws, A_ws, adj_out);
    h_kernel<<<256, 256, 0, stream>>>(A_ws, mean_ws, h_ws);
    e_kernel<<<dim3(64, 4), dim3(64, 4), 0, stream>>>(W2, h_ws, e_ws);
    softmax_out_kernel<<<512, 256, 0, stream>>>(x, e_ws, adj_out, out);
}